// Round 10
// baseline (386.927 us; speedup 1.0000x reference)
//
#include <hip/hip_runtime.h>

// AdultConnectomeNetwork: 3 layers of xt = A_sp @ (W_sp @ xt) + bias.
// Round 10: round-9 structure (packed kv {fp16 val, u16 col}, LDS-staged
// two-pass counting sort) with:
//  - SpMM: ONE ROW PER 64-LANE WAVE (halves h=0/1 take 4 of each 8 edges,
//    __shfl_xor(32) combine). Round 9 paired two different-degree rows per
//    wave -> max(d0,d1) masked waste + coarse latency hiding. Now uniform.
//  - pass1 CHUNK 4096: LDS 104KB -> ~54KB = 2 blocks/CU, 391 blocks.
//  - pass2 packs kv at load time; stages 10B/edge (u16 row + kvA + kvW),
//    ~52KB -> 3 blocks/CU.
// Hardening: computed indices clamped (logic error -> absmax fail, not fault).
// State layout: xt[N][32] (one 128B line per neuron), lane = batch column.

#define NN 50000
#define NNZ_E 1600000
#define NB (NN * 32)
#define CHUNK 4096
#define NBLK1 ((NNZ_E + CHUNK - 1) / CHUNK)      // 391
#define NBIN ((NN + 127) / 128)                  // 391 bins of 128 rows
#define NH (NBIN * NBLK1)                        // 152881
#define CAP2 5120                                // bin window cap (mean 4092, +16 sigma)
#define SCAN_NBLK ((NH + 255) / 256)             // 598

__device__ __forceinline__ int clampi(int v, int hi) {  // [0, hi]
    v = v < 0 ? 0 : v;
    return v > hi ? hi : v;
}

__device__ __forceinline__ unsigned pack_kv(float v, int c) {
    union { _Float16 h; unsigned short u; } cv;
    cv.h = (_Float16)v;
    return ((unsigned)cv.u << 16) | (unsigned)c;
}

__device__ __forceinline__ float kv_val(unsigned kv) {
    union { unsigned short u; _Float16 h; } cv;
    cv.u = (unsigned short)(kv >> 16);
    return (float)cv.h;
}

// Per-(chunk,bin) histogram matrix, bin-major. LDS only, no global atomics.
__global__ __launch_bounds__(256) void hist_kernel(const int* __restrict__ row,
                                                   int* __restrict__ hist1) {
    __shared__ int h[NBIN];
    int blk = blockIdx.x, tid = threadIdx.x;
    for (int j = tid; j < NBIN; j += 256) h[j] = 0;
    __syncthreads();
    int base = blk * CHUNK;
    int n = NNZ_E - base; if (n > CHUNK) n = CHUNK;
    for (int i = tid; i < n; i += 256)
        atomicAdd(&h[clampi(row[base + i], NN - 1) >> 7], 1);
    __syncthreads();
    for (int j = tid; j < NBIN; j += 256) hist1[j * NBLK1 + blk] = h[j];
}

// Exclusive scan within 256-blocks; bsum[blk] = block total.
__global__ void scan_local_kernel(int* __restrict__ data, int n, int* __restrict__ bsum) {
    __shared__ int s[256];
    int i = blockIdx.x * 256 + threadIdx.x;
    int v = (i < n) ? data[i] : 0;
    s[threadIdx.x] = v;
    __syncthreads();
    for (int off = 1; off < 256; off <<= 1) {
        int t = (threadIdx.x >= off) ? s[threadIdx.x - off] : 0;
        __syncthreads();
        s[threadIdx.x] += t;
        __syncthreads();
    }
    if (i < n) data[i] = s[threadIdx.x] - v;     // exclusive within block
    if (threadIdx.x == 255) bsum[blockIdx.x] = s[threadIdx.x];
}

// One block, 1024 threads: exclusive scan of bsum[m], m <= 1024 (m = 598).
__global__ void scan_tops_kernel(int* __restrict__ bsum, int m) {
    __shared__ int s[1024];
    int t = threadIdx.x;
    int v = (t < m) ? bsum[t] : 0;
    s[t] = v;
    __syncthreads();
    for (int off = 1; off < 1024; off <<= 1) {
        int u = (t >= off) ? s[t - off] : 0;
        __syncthreads();
        s[t] += u;
        __syncthreads();
    }
    if (t < m) bsum[t] = s[t] - v;               // exclusive
}

__global__ void fin_add_kernel(int* __restrict__ data, int n, const int* __restrict__ bsum) {
    int i = blockIdx.x * blockDim.x + threadIdx.x;
    if (i < n) data[i] += bsum[i >> 8];
}

// binstart[j] = scanned hist1[j*NBLK1]; sentinels.
__global__ void binstart_kernel(const int* __restrict__ hist1, int* __restrict__ binstart,
                                int* __restrict__ row_start) {
    int j = blockIdx.x * blockDim.x + threadIdx.x;
    if (j < NBIN) binstart[j] = hist1[j * NBLK1];
    if (j == 0) { binstart[NBIN] = NNZ_E; row_start[NN] = NNZ_E; }
}

// Pass 1: per-chunk in-LDS bin sort with FULL payload staging; sequential
// reads, dense burst writes. key = (row<<16)|col (both < 2^16).
__global__ __launch_bounds__(256) void pass1_kernel(
        const int* __restrict__ row, const int* __restrict__ col,
        const float* __restrict__ a, const float* __restrict__ w,
        const int* __restrict__ hist1_off,
        unsigned* __restrict__ k1, float* __restrict__ a1, float* __restrict__ w1) {
    __shared__ int h[NBIN];                  // counts -> placement cursors
    __shared__ int hscan[NBIN];              // block-local exclusive scan
    __shared__ int hoff[NBIN];               // global offsets for (bin, this blk)
    __shared__ int s256[256];
    __shared__ unsigned sKey[CHUNK];         // 16 KB
    __shared__ float sA[CHUNK];              // 16 KB
    __shared__ float sW[CHUNK];              // 16 KB
    int blk = blockIdx.x, tid = threadIdx.x;
    int base = blk * CHUNK;
    int n = NNZ_E - base; if (n > CHUNK) n = CHUNK;

    for (int j = tid; j < NBIN; j += 256) {
        h[j] = 0;
        hoff[j] = hist1_off[j * NBLK1 + blk];
    }
    __syncthreads();
    // local histogram (sequential global reads)
    for (int i = tid; i < n; i += 256)
        atomicAdd(&h[clampi(row[base + i], NN - 1) >> 7], 1);
    __syncthreads();
    // block-local exclusive scan of h (2 bins/thread: 512 >= 391)
    int j0 = tid * 2, j1 = tid * 2 + 1;
    int c0 = (j0 < NBIN) ? h[j0] : 0;
    int c1 = (j1 < NBIN) ? h[j1] : 0;
    int tsum = c0 + c1;
    s256[tid] = tsum;
    __syncthreads();
    for (int off = 1; off < 256; off <<= 1) {
        int t = (tid >= off) ? s256[tid - off] : 0;
        __syncthreads();
        s256[tid] += t;
        __syncthreads();
    }
    int ex = s256[tid] - tsum;
    __syncthreads();                         // reads of h done before overwrite
    if (j0 < NBIN) { hscan[j0] = ex;      h[j0] = ex; }
    if (j1 < NBIN) { hscan[j1] = ex + c0; h[j1] = ex + c0; }
    __syncthreads();
    // placement: full payload into LDS-sorted slots (sequential global reads)
    for (int i = tid; i < n; i += 256) {
        int r = clampi(row[base + i], NN - 1);
        int c = clampi(col[base + i], NN - 1);
        int bin = r >> 7;
        int p = atomicAdd(&h[bin], 1);       // LDS cursor, block-private
        p = clampi(p, n - 1);                // hardening
        sKey[p] = ((unsigned)r << 16) | (unsigned)c;
        sA[p] = a[base + i];
        sW[p] = w[base + i];
    }
    __syncthreads();
    // dense burst write-back: sequential LDS reads, contiguous runs per bin.
    for (int p = tid; p < n; p += 256) {
        unsigned key = sKey[p];
        int bin = (int)(key >> 23);          // = row >> 7
        int d = clampi(hoff[bin] + (p - hscan[bin]), NNZ_E - 1);
        k1[d] = key;
        a1[d] = sA[p];
        w1[d] = sW[p];
    }
}

// Pass 2: one block per 128-row bin window. Row hist+scan in LDS, writes
// row_start, then places packed kvA/kvW row-sorted IN-PLACE into a1/w1.
// kv packed at LOAD time: stages 10B/edge (u16 rowlocal + kvA + kvW).
__global__ __launch_bounds__(256) void pass2_kernel(
        const unsigned* __restrict__ k1, float* __restrict__ a1, float* __restrict__ w1,
        const int* __restrict__ binstart, int* __restrict__ row_start) {
    __shared__ unsigned short sR[CAP2];      // 10 KB
    __shared__ unsigned sKvA[CAP2];          // 20 KB
    __shared__ unsigned sKvW[CAP2];          // 20 KB
    __shared__ int rh[128];
    __shared__ int rs[128];
    __shared__ int cur[128];
    int bin = blockIdx.x, tid = threadIdx.x;
    int r0 = bin << 7;
    int rows = NN - r0; if (rows > 128) rows = 128;
    int base = clampi(binstart[bin], NNZ_E);
    int size = clampi(binstart[bin + 1], NNZ_E) - base;
    if (size < 0) size = 0;
    bool fits = (size <= CAP2);

    if (tid < 128) rh[tid] = 0;
    __syncthreads();
    for (int i = tid; i < size; i += 256) {
        unsigned key = k1[base + i];
        int rl = (key >> 16) & 127;
        atomicAdd(&rh[rl], 1);
        if (fits) {
            int c = (int)(key & 0xFFFFu);
            sR[i] = (unsigned short)rl;
            sKvA[i] = pack_kv(a1[base + i], c);
            sKvW[i] = pack_kv(w1[base + i], c);
        }
    }
    __syncthreads();
    int v = (tid < 128) ? rh[tid] : 0;
    if (tid < 128) rs[tid] = v;
    __syncthreads();
    for (int off = 1; off < 128; off <<= 1) {
        int t = (tid >= off && tid < 128) ? rs[tid - off] : 0;
        __syncthreads();
        if (tid < 128) rs[tid] += t;
        __syncthreads();
    }
    int ex = (tid < 128) ? rs[tid] - v : 0;
    if (tid < 128) cur[tid] = ex;
    if (tid < rows) row_start[r0 + tid] = base + clampi(ex, size);
    __syncthreads();
    if (!fits) return;                       // row_start still valid/bounded
    unsigned* kvA = (unsigned*)a1;
    unsigned* kvW = (unsigned*)w1;
    for (int i = tid; i < size; i += 256) {
        int rl = sR[i];
        int p = atomicAdd(&cur[rl], 1);
        p = clampi(p, size - 1);             // hardening
        kvA[base + p] = sKvA[i];
        kvW[base + p] = sKvW[i];
    }
}

__global__ void transpose_in_kernel(const float* __restrict__ x,
                                    float* __restrict__ xt) {
    int i = blockIdx.x * blockDim.x + threadIdx.x;  // i = n*32 + b
    if (i < NB) {
        int n = i >> 5;
        int b = i & 31;
        xt[i] = x[b * NN + n];
    }
}

// ONE ROW PER 64-LANE WAVE. Half h handles 4 of each 8 edges; lane = batch
// column within half. __shfl_xor(32) combines the two halves at the end.
// Uniform per-wave trip count (no cross-row divergence), 50K waves.
template <int WITH_BIAS>
__global__ __launch_bounds__(256) void spmm_kernel(
        const unsigned* __restrict__ kv, const int* __restrict__ row_start,
        const float* __restrict__ in, float* __restrict__ out,
        const float* __restrict__ bias) {
    int r = (blockIdx.x * 256 + threadIdx.x) >> 6;   // one row per wave
    int lane = threadIdx.x & 63;
    int h = lane >> 5;
    int b = lane & 31;
    if (r >= NN) return;
    int s = clampi(row_start[r], NNZ_E);
    int e = clampi(row_start[r + 1], NNZ_E);
    if (e < s) e = s;
    float acc = (WITH_BIAS && h == 0) ? bias[r] : 0.0f;
    int i = s;
    for (; i + 8 <= e; i += 8) {             // 8 edges/iter: h*4 + q
        unsigned k[4]; float g[4];
#pragma unroll
        for (int q = 0; q < 4; ++q) k[q] = kv[i + h * 4 + q];
#pragma unroll
        for (int q = 0; q < 4; ++q) g[q] = in[((k[q] & 0xFFFFu) << 5) + b];
#pragma unroll
        for (int q = 0; q < 4; ++q) acc += kv_val(k[q]) * g[q];
    }
    for (int ii = i + h; ii < e; ii += 2) {  // remainder: stride-2 per half
        unsigned k = kv[ii];
        acc += kv_val(k) * in[((k & 0xFFFFu) << 5) + b];
    }
    float tot = acc + __shfl_xor(acc, 32);
    if (h == 0) out[(r << 5) + b] = tot;
}

__global__ void transpose_out_kernel(const float* __restrict__ xt,
                                     float* __restrict__ out) {
    int i = blockIdx.x * blockDim.x + threadIdx.x;  // i = b*N + n (coalesced write)
    if (i < NB) {
        int b = i / NN;
        int n = i - b * NN;
        out[i] = xt[(n << 5) + b];
    }
}

extern "C" void kernel_launch(void* const* d_in, const int* in_sizes, int n_in,
                              void* d_out, int out_size, void* d_ws, size_t ws_size,
                              hipStream_t stream) {
    const float* x        = (const float*)d_in[0];
    const float* adj_vals = (const float*)d_in[1];
    const float* w_vals   = (const float*)d_in[2];
    const float* bias     = (const float*)d_in[3];
    const int*   row      = (const int*)d_in[4];
    const int*   col      = (const int*)d_in[5];
    float* out = (float*)d_out;

    // Workspace (~32.9 MB; >= 38.9 MB proven available in round 3)
    unsigned* k1       = (unsigned*)d_ws;          // NNZ_E (row<<16|col keys)
    float*    a1       = (float*)(k1 + NNZ_E);     // NNZ_E -> becomes kvA (u32)
    float*    w1       = a1 + NNZ_E;               // NNZ_E -> becomes kvW (u32)
    float*    xt       = w1 + NNZ_E;               // NB
    float*    tmp      = xt + NB;                  // NB
    int*   hist1       = (int*)(tmp + NB);         // NH (scanned in place)
    int*   bsumB       = hist1 + NH;               // 1024
    int*   binstart    = bsumB + 1024;             // NBIN+1 (+pad)
    int*   row_start   = binstart + NBIN + 8;      // NN+1

    const int BS = 256;
    const int grid_nb   = (NB + BS - 1) / BS;      // 6250
    const int grid_spmm = (NN * 64 + BS - 1) / BS; // 12500

    // ---- (chunk,bin) histogram matrix + bin-major scan ----
    hist_kernel<<<NBLK1, BS, 0, stream>>>(row, hist1);
    scan_local_kernel<<<SCAN_NBLK, BS, 0, stream>>>(hist1, NH, bsumB);
    scan_tops_kernel<<<1, 1024, 0, stream>>>(bsumB, SCAN_NBLK);
    fin_add_kernel<<<SCAN_NBLK, BS, 0, stream>>>(hist1, NH, bsumB);
    binstart_kernel<<<(NBIN + 1 + BS - 1) / BS, BS, 0, stream>>>(hist1, binstart, row_start);

    // ---- two-pass sort: bin-group (LDS payload staging) then row-sort+pack ----
    pass1_kernel<<<NBLK1, BS, 0, stream>>>(row, col, adj_vals, w_vals,
                                           hist1, k1, a1, w1);
    pass2_kernel<<<NBIN, BS, 0, stream>>>(k1, a1, w1, binstart, row_start);

    const unsigned* kvA = (const unsigned*)a1;
    const unsigned* kvW = (const unsigned*)w1;

    // ---- dense passes ----
    transpose_in_kernel<<<grid_nb, BS, 0, stream>>>(x, xt);
    for (int layer = 0; layer < 3; ++layer) {
        spmm_kernel<0><<<grid_spmm, BS, 0, stream>>>(kvW, row_start, xt, tmp, nullptr);
        spmm_kernel<1><<<grid_spmm, BS, 0, stream>>>(kvA, row_start, tmp, xt, bias);
    }
    transpose_out_kernel<<<grid_nb, BS, 0, stream>>>(xt, out);
}

// Round 11
// 338.675 us; speedup vs baseline: 1.1425x; 1.1425x over previous
//
#include <hip/hip_runtime.h>

// AdultConnectomeNetwork: 3 layers of xt = A_sp @ (W_sp @ xt) + bias.
// Round 11: round-9 structure with targeted fixes.
//  - pass1 CHUNK 6144 -> 261 blocks: covers all 256 CUs (round-9's 196-block
//    grid left 1/4 of the machine idle: OccupancyPercent 5.6%), while only
//    growing the hist/scan matrix 1.33x (round-10's CHUNK 4096 doubled it
//    and regressed).
//  - SpMM: 2 rows per wave (half-wave per row, round-9 shape — round-10's
//    one-row-per-wave regressed) + SOFTWARE PIPELINE: next 8 kv words
//    preloaded while current 8 gathers/FMAs execute, hiding the
//    kv-load->gather dependency that exposes latency on ~4-iteration rows.
//  - pass2 from round 10: packs kv {fp16 val, u16 col} at load time,
//    stages 10B/edge.
// Hardening: computed indices clamped (logic error -> absmax fail, not fault).
// State layout: xt[N][32] (one 128B line per neuron), lane = batch column.

#define NN 50000
#define NNZ_E 1600000
#define NB (NN * 32)
#define CHUNK 6144
#define NBLK1 ((NNZ_E + CHUNK - 1) / CHUNK)      // 261
#define NBIN ((NN + 127) / 128)                  // 391 bins of 128 rows
#define NH (NBIN * NBLK1)                        // 102051
#define CAP2 5120                                // bin window cap (mean 4092, +16 sigma)
#define SCAN_NBLK ((NH + 255) / 256)             // 399

__device__ __forceinline__ int clampi(int v, int hi) {  // [0, hi]
    v = v < 0 ? 0 : v;
    return v > hi ? hi : v;
}

__device__ __forceinline__ unsigned pack_kv(float v, int c) {
    union { _Float16 h; unsigned short u; } cv;
    cv.h = (_Float16)v;
    return ((unsigned)cv.u << 16) | (unsigned)c;
}

__device__ __forceinline__ float kv_val(unsigned kv) {
    union { unsigned short u; _Float16 h; } cv;
    cv.u = (unsigned short)(kv >> 16);
    return (float)cv.h;
}

// Per-(chunk,bin) histogram matrix, bin-major. LDS only, no global atomics.
__global__ __launch_bounds__(256) void hist_kernel(const int* __restrict__ row,
                                                   int* __restrict__ hist1) {
    __shared__ int h[NBIN];
    int blk = blockIdx.x, tid = threadIdx.x;
    for (int j = tid; j < NBIN; j += 256) h[j] = 0;
    __syncthreads();
    int base = blk * CHUNK;
    int n = NNZ_E - base; if (n > CHUNK) n = CHUNK;
    for (int i = tid; i < n; i += 256)
        atomicAdd(&h[clampi(row[base + i], NN - 1) >> 7], 1);
    __syncthreads();
    for (int j = tid; j < NBIN; j += 256) hist1[j * NBLK1 + blk] = h[j];
}

// Exclusive scan within 256-blocks; bsum[blk] = block total.
__global__ void scan_local_kernel(int* __restrict__ data, int n, int* __restrict__ bsum) {
    __shared__ int s[256];
    int i = blockIdx.x * 256 + threadIdx.x;
    int v = (i < n) ? data[i] : 0;
    s[threadIdx.x] = v;
    __syncthreads();
    for (int off = 1; off < 256; off <<= 1) {
        int t = (threadIdx.x >= off) ? s[threadIdx.x - off] : 0;
        __syncthreads();
        s[threadIdx.x] += t;
        __syncthreads();
    }
    if (i < n) data[i] = s[threadIdx.x] - v;     // exclusive within block
    if (threadIdx.x == 255) bsum[blockIdx.x] = s[threadIdx.x];
}

// One block, 512 threads: exclusive scan of bsum[m], m <= 512 (m = 399).
__global__ void scan_tops_kernel(int* __restrict__ bsum, int m) {
    __shared__ int s[512];
    int t = threadIdx.x;
    int v = (t < m) ? bsum[t] : 0;
    s[t] = v;
    __syncthreads();
    for (int off = 1; off < 512; off <<= 1) {
        int u = (t >= off) ? s[t - off] : 0;
        __syncthreads();
        s[t] += u;
        __syncthreads();
    }
    if (t < m) bsum[t] = s[t] - v;               // exclusive
}

__global__ void fin_add_kernel(int* __restrict__ data, int n, const int* __restrict__ bsum) {
    int i = blockIdx.x * blockDim.x + threadIdx.x;
    if (i < n) data[i] += bsum[i >> 8];
}

// binstart[j] = scanned hist1[j*NBLK1]; sentinels.
__global__ void binstart_kernel(const int* __restrict__ hist1, int* __restrict__ binstart,
                                int* __restrict__ row_start) {
    int j = blockIdx.x * blockDim.x + threadIdx.x;
    if (j < NBIN) binstart[j] = hist1[j * NBLK1];
    if (j == 0) { binstart[NBIN] = NNZ_E; row_start[NN] = NNZ_E; }
}

// Pass 1: per-chunk in-LDS bin sort with FULL payload staging; sequential
// reads, dense burst writes. key = (row<<16)|col (both < 2^16).
__global__ __launch_bounds__(256) void pass1_kernel(
        const int* __restrict__ row, const int* __restrict__ col,
        const float* __restrict__ a, const float* __restrict__ w,
        const int* __restrict__ hist1_off,
        unsigned* __restrict__ k1, float* __restrict__ a1, float* __restrict__ w1) {
    __shared__ int h[NBIN];                  // counts -> placement cursors
    __shared__ int hscan[NBIN];              // block-local exclusive scan
    __shared__ int hoff[NBIN];               // global offsets for (bin, this blk)
    __shared__ int s256[256];
    __shared__ unsigned sKey[CHUNK];         // 24 KB
    __shared__ float sA[CHUNK];              // 24 KB
    __shared__ float sW[CHUNK];              // 24 KB
    int blk = blockIdx.x, tid = threadIdx.x;
    int base = blk * CHUNK;
    int n = NNZ_E - base; if (n > CHUNK) n = CHUNK;

    for (int j = tid; j < NBIN; j += 256) {
        h[j] = 0;
        hoff[j] = hist1_off[j * NBLK1 + blk];
    }
    __syncthreads();
    // local histogram (sequential global reads)
    for (int i = tid; i < n; i += 256)
        atomicAdd(&h[clampi(row[base + i], NN - 1) >> 7], 1);
    __syncthreads();
    // block-local exclusive scan of h (2 bins/thread: 512 >= 391)
    int j0 = tid * 2, j1 = tid * 2 + 1;
    int c0 = (j0 < NBIN) ? h[j0] : 0;
    int c1 = (j1 < NBIN) ? h[j1] : 0;
    int tsum = c0 + c1;
    s256[tid] = tsum;
    __syncthreads();
    for (int off = 1; off < 256; off <<= 1) {
        int t = (tid >= off) ? s256[tid - off] : 0;
        __syncthreads();
        s256[tid] += t;
        __syncthreads();
    }
    int ex = s256[tid] - tsum;
    __syncthreads();                         // reads of h done before overwrite
    if (j0 < NBIN) { hscan[j0] = ex;      h[j0] = ex; }
    if (j1 < NBIN) { hscan[j1] = ex + c0; h[j1] = ex + c0; }
    __syncthreads();
    // placement: full payload into LDS-sorted slots (sequential global reads)
    for (int i = tid; i < n; i += 256) {
        int r = clampi(row[base + i], NN - 1);
        int c = clampi(col[base + i], NN - 1);
        int bin = r >> 7;
        int p = atomicAdd(&h[bin], 1);       // LDS cursor, block-private
        p = clampi(p, n - 1);                // hardening
        sKey[p] = ((unsigned)r << 16) | (unsigned)c;
        sA[p] = a[base + i];
        sW[p] = w[base + i];
    }
    __syncthreads();
    // dense burst write-back: sequential LDS reads, contiguous runs per bin.
    for (int p = tid; p < n; p += 256) {
        unsigned key = sKey[p];
        int bin = (int)(key >> 23);          // = row >> 7
        int d = clampi(hoff[bin] + (p - hscan[bin]), NNZ_E - 1);
        k1[d] = key;
        a1[d] = sA[p];
        w1[d] = sW[p];
    }
}

// Pass 2: one block per 128-row bin window. Row hist+scan in LDS, writes
// row_start, then places packed kvA/kvW row-sorted IN-PLACE into a1/w1.
// kv packed at LOAD time: stages 10B/edge (u16 rowlocal + kvA + kvW).
__global__ __launch_bounds__(256) void pass2_kernel(
        const unsigned* __restrict__ k1, float* __restrict__ a1, float* __restrict__ w1,
        const int* __restrict__ binstart, int* __restrict__ row_start) {
    __shared__ unsigned short sR[CAP2];      // 10 KB
    __shared__ unsigned sKvA[CAP2];          // 20 KB
    __shared__ unsigned sKvW[CAP2];          // 20 KB
    __shared__ int rh[128];
    __shared__ int rs[128];
    __shared__ int cur[128];
    int bin = blockIdx.x, tid = threadIdx.x;
    int r0 = bin << 7;
    int rows = NN - r0; if (rows > 128) rows = 128;
    int base = clampi(binstart[bin], NNZ_E);
    int size = clampi(binstart[bin + 1], NNZ_E) - base;
    if (size < 0) size = 0;
    bool fits = (size <= CAP2);

    if (tid < 128) rh[tid] = 0;
    __syncthreads();
    for (int i = tid; i < size; i += 256) {
        unsigned key = k1[base + i];
        int rl = (key >> 16) & 127;
        atomicAdd(&rh[rl], 1);
        if (fits) {
            int c = (int)(key & 0xFFFFu);
            sR[i] = (unsigned short)rl;
            sKvA[i] = pack_kv(a1[base + i], c);
            sKvW[i] = pack_kv(w1[base + i], c);
        }
    }
    __syncthreads();
    int v = (tid < 128) ? rh[tid] : 0;
    if (tid < 128) rs[tid] = v;
    __syncthreads();
    for (int off = 1; off < 128; off <<= 1) {
        int t = (tid >= off && tid < 128) ? rs[tid - off] : 0;
        __syncthreads();
        if (tid < 128) rs[tid] += t;
        __syncthreads();
    }
    int ex = (tid < 128) ? rs[tid] - v : 0;
    if (tid < 128) cur[tid] = ex;
    if (tid < rows) row_start[r0 + tid] = base + clampi(ex, size);
    __syncthreads();
    if (!fits) return;                       // row_start still valid/bounded
    unsigned* kvA = (unsigned*)a1;
    unsigned* kvW = (unsigned*)w1;
    for (int i = tid; i < size; i += 256) {
        int rl = sR[i];
        int p = atomicAdd(&cur[rl], 1);
        p = clampi(p, size - 1);             // hardening
        kvA[base + p] = sKvA[i];
        kvW[base + p] = sKvW[i];
    }
}

__global__ void transpose_in_kernel(const float* __restrict__ x,
                                    float* __restrict__ xt) {
    int i = blockIdx.x * blockDim.x + threadIdx.x;  // i = n*32 + b
    if (i < NB) {
        int n = i >> 5;
        int b = i & 31;
        xt[i] = x[b * NN + n];
    }
}

// One 32-lane half-wave per row; lane = batch column. Software-pipelined:
// next 8 kv preloaded while current 8 gathers/FMAs execute.
template <int WITH_BIAS>
__global__ __launch_bounds__(256) void spmm_kernel(
        const unsigned* __restrict__ kv, const int* __restrict__ row_start,
        const float* __restrict__ in, float* __restrict__ out,
        const float* __restrict__ bias) {
    int t = blockIdx.x * 256 + threadIdx.x;
    int r = t >> 5;
    int b = t & 31;
    if (r >= NN) return;
    int s = clampi(row_start[r], NNZ_E);
    int e = clampi(row_start[r + 1], NNZ_E);
    if (e < s) e = s;
    float acc0 = WITH_BIAS ? bias[r] : 0.0f;
    float acc1 = 0.0f;
    int efull = s + ((e - s) & ~7);
    int i = s;
    unsigned k[8];
    if (i < efull) {
#pragma unroll
        for (int j = 0; j < 8; ++j) k[j] = kv[i + j];
    }
    while (i < efull) {
        float g[8];
#pragma unroll
        for (int j = 0; j < 8; ++j) g[j] = in[((k[j] & 0xFFFFu) << 5) + b];
        i += 8;
        unsigned kn[8];
        if (i < efull) {
#pragma unroll
            for (int j = 0; j < 8; ++j) kn[j] = kv[i + j];
        }
#pragma unroll
        for (int j = 0; j < 8; ++j) {
            if (j & 1) acc1 += kv_val(k[j]) * g[j];
            else       acc0 += kv_val(k[j]) * g[j];
        }
#pragma unroll
        for (int j = 0; j < 8; ++j) k[j] = kn[j];
    }
    for (; i < e; ++i) {
        unsigned kk = kv[i];
        acc0 += kv_val(kk) * in[((kk & 0xFFFFu) << 5) + b];
    }
    out[(r << 5) + b] = acc0 + acc1;
}

__global__ void transpose_out_kernel(const float* __restrict__ xt,
                                     float* __restrict__ out) {
    int i = blockIdx.x * blockDim.x + threadIdx.x;  // i = b*N + n (coalesced write)
    if (i < NB) {
        int b = i / NN;
        int n = i - b * NN;
        out[i] = xt[(n << 5) + b];
    }
}

extern "C" void kernel_launch(void* const* d_in, const int* in_sizes, int n_in,
                              void* d_out, int out_size, void* d_ws, size_t ws_size,
                              hipStream_t stream) {
    const float* x        = (const float*)d_in[0];
    const float* adj_vals = (const float*)d_in[1];
    const float* w_vals   = (const float*)d_in[2];
    const float* bias     = (const float*)d_in[3];
    const int*   row      = (const int*)d_in[4];
    const int*   col      = (const int*)d_in[5];
    float* out = (float*)d_out;

    // Workspace (~32.7 MB; ws_size = 256 MiB per round-10 fill evidence)
    unsigned* k1       = (unsigned*)d_ws;          // NNZ_E (row<<16|col keys)
    float*    a1       = (float*)(k1 + NNZ_E);     // NNZ_E -> becomes kvA (u32)
    float*    w1       = a1 + NNZ_E;               // NNZ_E -> becomes kvW (u32)
    float*    xt       = w1 + NNZ_E;               // NB
    float*    tmp      = xt + NB;                  // NB
    int*   hist1       = (int*)(tmp + NB);         // NH (scanned in place)
    int*   bsumB       = hist1 + NH;               // 512
    int*   binstart    = bsumB + 512;              // NBIN+1 (+pad)
    int*   row_start   = binstart + NBIN + 8;      // NN+1

    const int BS = 256;
    const int grid_nb = (NB + BS - 1) / BS;        // 6250

    // ---- (chunk,bin) histogram matrix + bin-major scan ----
    hist_kernel<<<NBLK1, BS, 0, stream>>>(row, hist1);
    scan_local_kernel<<<SCAN_NBLK, BS, 0, stream>>>(hist1, NH, bsumB);
    scan_tops_kernel<<<1, 512, 0, stream>>>(bsumB, SCAN_NBLK);
    fin_add_kernel<<<SCAN_NBLK, BS, 0, stream>>>(hist1, NH, bsumB);
    binstart_kernel<<<(NBIN + 1 + BS - 1) / BS, BS, 0, stream>>>(hist1, binstart, row_start);

    // ---- two-pass sort: bin-group (LDS payload staging) then row-sort+pack ----
    pass1_kernel<<<NBLK1, BS, 0, stream>>>(row, col, adj_vals, w_vals,
                                           hist1, k1, a1, w1);
    pass2_kernel<<<NBIN, BS, 0, stream>>>(k1, a1, w1, binstart, row_start);

    const unsigned* kvA = (const unsigned*)a1;
    const unsigned* kvW = (const unsigned*)w1;

    // ---- dense passes ----
    transpose_in_kernel<<<grid_nb, BS, 0, stream>>>(x, xt);
    for (int layer = 0; layer < 3; ++layer) {
        spmm_kernel<0><<<grid_nb, BS, 0, stream>>>(kvW, row_start, xt, tmp, nullptr);
        spmm_kernel<1><<<grid_nb, BS, 0, stream>>>(kvA, row_start, tmp, xt, bias);
    }
    transpose_out_kernel<<<grid_nb, BS, 0, stream>>>(xt, out);
}

// Round 13
// 295.440 us; speedup vs baseline: 1.3097x; 1.1463x over previous
//
#include <hip/hip_runtime.h>

// AdultConnectomeNetwork: 3 layers of xt = A_sp @ (W_sp @ xt) + bias.
// Round 13: scaled fp16 state (round-12 retry with the overflow fixed).
//  - Round 12 range analysis missed the MEAN path: bias=1 + E[val]=0.5 make
//    E[xt_l] grow 256x per layer -> xt_3 ~ 65536 ~ fp16 max -> inf.
//  - Fix: state_l = xt_l * 256^-l (exact pow2). A-pass epilogue:
//    out = acc/256 + bias*256^-(l+1); final transpose multiplies by 2^24.
//    State stays O(1e-3..1e1); overflow impossible; precision cost ~2e-4 rel.
//  - fp16 state [N][32] = 64B/neuron: 3.2MB working set fits 4MB/XCD L2;
//    gather + state-write traffic both halve.
//  - Sort improvements from round 12 (provably uninvolved in the inf):
//    pass1 stages 8B/edge (key + packed {fp16 a, fp16 w}) -> ~54KB LDS at
//    CHUNK 6144 = 2 blocks/CU (round-11: 78KB = 1); writes 12.8MB not 19.2.
//    pass2 stages 8B/edge, derives kvA/kvW in place.
//  - SpMM: half-wave per row, software-pipelined unroll-8 (round-11 shape).
// Hardening: computed indices clamped (logic error -> absmax fail, not fault).

#define NN 50000
#define NNZ_E 1600000
#define NB (NN * 32)
#define CHUNK 6144
#define NBLK1 ((NNZ_E + CHUNK - 1) / CHUNK)      // 261
#define NBIN ((NN + 127) / 128)                  // 391 bins of 128 rows
#define NH (NBIN * NBLK1)                        // 102051
#define CAP2 5120                                // bin window cap (mean 4092, +16 sigma)
#define SCAN_NBLK ((NH + 255) / 256)             // 399

__device__ __forceinline__ int clampi(int v, int hi) {  // [0, hi]
    v = v < 0 ? 0 : v;
    return v > hi ? hi : v;
}

__device__ __forceinline__ unsigned short f2h(float v) {
    union { _Float16 h; unsigned short u; } cv;
    cv.h = (_Float16)v;
    return cv.u;
}

__device__ __forceinline__ float kv_val(unsigned kv) {
    union { unsigned short u; _Float16 h; } cv;
    cv.u = (unsigned short)(kv >> 16);
    return (float)cv.h;
}

// Per-(chunk,bin) histogram matrix, bin-major. LDS only, no global atomics.
__global__ __launch_bounds__(256) void hist_kernel(const int* __restrict__ row,
                                                   int* __restrict__ hist1) {
    __shared__ int h[NBIN];
    int blk = blockIdx.x, tid = threadIdx.x;
    for (int j = tid; j < NBIN; j += 256) h[j] = 0;
    __syncthreads();
    int base = blk * CHUNK;
    int n = NNZ_E - base; if (n > CHUNK) n = CHUNK;
    for (int i = tid; i < n; i += 256)
        atomicAdd(&h[clampi(row[base + i], NN - 1) >> 7], 1);
    __syncthreads();
    for (int j = tid; j < NBIN; j += 256) hist1[j * NBLK1 + blk] = h[j];
}

// Exclusive scan within 256-blocks; bsum[blk] = block total.
__global__ void scan_local_kernel(int* __restrict__ data, int n, int* __restrict__ bsum) {
    __shared__ int s[256];
    int i = blockIdx.x * 256 + threadIdx.x;
    int v = (i < n) ? data[i] : 0;
    s[threadIdx.x] = v;
    __syncthreads();
    for (int off = 1; off < 256; off <<= 1) {
        int t = (threadIdx.x >= off) ? s[threadIdx.x - off] : 0;
        __syncthreads();
        s[threadIdx.x] += t;
        __syncthreads();
    }
    if (i < n) data[i] = s[threadIdx.x] - v;     // exclusive within block
    if (threadIdx.x == 255) bsum[blockIdx.x] = s[threadIdx.x];
}

// One block, 512 threads: exclusive scan of bsum[m], m <= 512 (m = 399).
__global__ void scan_tops_kernel(int* __restrict__ bsum, int m) {
    __shared__ int s[512];
    int t = threadIdx.x;
    int v = (t < m) ? bsum[t] : 0;
    s[t] = v;
    __syncthreads();
    for (int off = 1; off < 512; off <<= 1) {
        int u = (t >= off) ? s[t - off] : 0;
        __syncthreads();
        s[t] += u;
        __syncthreads();
    }
    if (t < m) bsum[t] = s[t] - v;               // exclusive
}

__global__ void fin_add_kernel(int* __restrict__ data, int n, const int* __restrict__ bsum) {
    int i = blockIdx.x * blockDim.x + threadIdx.x;
    if (i < n) data[i] += bsum[i >> 8];
}

// binstart[j] = scanned hist1[j*NBLK1]; sentinels.
__global__ void binstart_kernel(const int* __restrict__ hist1, int* __restrict__ binstart,
                                int* __restrict__ row_start) {
    int j = blockIdx.x * blockDim.x + threadIdx.x;
    if (j < NBIN) binstart[j] = hist1[j * NBLK1];
    if (j == 0) { binstart[NBIN] = NNZ_E; row_start[NN] = NNZ_E; }
}

// Pass 1: per-chunk in-LDS bin sort, payload staged as 8B/edge
// (key u32 + {fp16 a, fp16 w} u32); sequential reads, dense burst writes.
// key = (row<<16)|col (both < 2^16).
__global__ __launch_bounds__(256) void pass1_kernel(
        const int* __restrict__ row, const int* __restrict__ col,
        const float* __restrict__ a, const float* __restrict__ w,
        const int* __restrict__ hist1_off,
        unsigned* __restrict__ k1, unsigned* __restrict__ aw1) {
    __shared__ int h[NBIN];                  // counts -> placement cursors
    __shared__ int hscan[NBIN];              // block-local exclusive scan
    __shared__ int hoff[NBIN];               // global offsets for (bin, this blk)
    __shared__ int s256[256];
    __shared__ unsigned sKey[CHUNK];         // 24 KB
    __shared__ unsigned sAW[CHUNK];          // 24 KB
    int blk = blockIdx.x, tid = threadIdx.x;
    int base = blk * CHUNK;
    int n = NNZ_E - base; if (n > CHUNK) n = CHUNK;

    for (int j = tid; j < NBIN; j += 256) {
        h[j] = 0;
        hoff[j] = hist1_off[j * NBLK1 + blk];
    }
    __syncthreads();
    // local histogram (sequential global reads)
    for (int i = tid; i < n; i += 256)
        atomicAdd(&h[clampi(row[base + i], NN - 1) >> 7], 1);
    __syncthreads();
    // block-local exclusive scan of h (2 bins/thread: 512 >= 391)
    int j0 = tid * 2, j1 = tid * 2 + 1;
    int c0 = (j0 < NBIN) ? h[j0] : 0;
    int c1 = (j1 < NBIN) ? h[j1] : 0;
    int tsum = c0 + c1;
    s256[tid] = tsum;
    __syncthreads();
    for (int off = 1; off < 256; off <<= 1) {
        int t = (tid >= off) ? s256[tid - off] : 0;
        __syncthreads();
        s256[tid] += t;
        __syncthreads();
    }
    int ex = s256[tid] - tsum;
    __syncthreads();                         // reads of h done before overwrite
    if (j0 < NBIN) { hscan[j0] = ex;      h[j0] = ex; }
    if (j1 < NBIN) { hscan[j1] = ex + c0; h[j1] = ex + c0; }
    __syncthreads();
    // placement: payload into LDS-sorted slots (sequential global reads)
    for (int i = tid; i < n; i += 256) {
        int r = clampi(row[base + i], NN - 1);
        int c = clampi(col[base + i], NN - 1);
        int bin = r >> 7;
        int p = atomicAdd(&h[bin], 1);       // LDS cursor, block-private
        p = clampi(p, n - 1);                // hardening
        sKey[p] = ((unsigned)r << 16) | (unsigned)c;
        sAW[p] = ((unsigned)f2h(a[base + i]) << 16) | (unsigned)f2h(w[base + i]);
    }
    __syncthreads();
    // dense burst write-back: sequential LDS reads, contiguous runs per bin.
    for (int p = tid; p < n; p += 256) {
        unsigned key = sKey[p];
        int bin = (int)(key >> 23);          // = row >> 7
        int d = clampi(hoff[bin] + (p - hscan[bin]), NNZ_E - 1);
        k1[d] = key;
        aw1[d] = sAW[p];
    }
}

// Pass 2: one block per 128-row bin window. Row hist+scan in LDS, writes
// row_start, then derives kvA/kvW row-sorted IN-PLACE over k1/aw1.
// kvA = (fp16 a << 16)|col, kvW = (fp16 w << 16)|col.
__global__ __launch_bounds__(256) void pass2_kernel(
        unsigned* __restrict__ k1, unsigned* __restrict__ aw1,
        const int* __restrict__ binstart, int* __restrict__ row_start) {
    __shared__ unsigned sKey[CAP2];          // 20 KB
    __shared__ unsigned sAW[CAP2];           // 20 KB
    __shared__ int rh[128];
    __shared__ int rs[128];
    __shared__ int cur[128];
    int bin = blockIdx.x, tid = threadIdx.x;
    int r0 = bin << 7;
    int rows = NN - r0; if (rows > 128) rows = 128;
    int base = clampi(binstart[bin], NNZ_E);
    int size = clampi(binstart[bin + 1], NNZ_E) - base;
    if (size < 0) size = 0;
    bool fits = (size <= CAP2);

    if (tid < 128) rh[tid] = 0;
    __syncthreads();
    for (int i = tid; i < size; i += 256) {
        unsigned key = k1[base + i];
        atomicAdd(&rh[(key >> 16) & 127], 1);
        if (fits) { sKey[i] = key; sAW[i] = aw1[base + i]; }
    }
    __syncthreads();
    int v = (tid < 128) ? rh[tid] : 0;
    if (tid < 128) rs[tid] = v;
    __syncthreads();
    for (int off = 1; off < 128; off <<= 1) {
        int t = (tid >= off && tid < 128) ? rs[tid - off] : 0;
        __syncthreads();
        if (tid < 128) rs[tid] += t;
        __syncthreads();
    }
    int ex = (tid < 128) ? rs[tid] - v : 0;
    if (tid < 128) cur[tid] = ex;
    if (tid < rows) row_start[r0 + tid] = base + clampi(ex, size);
    __syncthreads();
    if (!fits) return;                       // row_start still valid/bounded
    // k1 becomes kvA, aw1 becomes kvW (all reads completed above).
    for (int i = tid; i < size; i += 256) {
        unsigned key = sKey[i];
        unsigned aw  = sAW[i];
        int rl = (key >> 16) & 127;
        int p = atomicAdd(&cur[rl], 1);
        p = clampi(p, size - 1);             // hardening
        unsigned c = key & 0xFFFFu;
        k1[base + p]  = (aw & 0xFFFF0000u) | c;    // kvA
        aw1[base + p] = (aw << 16) | c;            // kvW
    }
}

__global__ void transpose_in_kernel(const float* __restrict__ x,
                                    _Float16* __restrict__ xt) {
    int i = blockIdx.x * blockDim.x + threadIdx.x;  // i = n*32 + b
    if (i < NB) {
        int n = i >> 5;
        int b = i & 31;
        xt[i] = (_Float16)x[b * NN + n];
    }
}

// One 32-lane half-wave per row; lane = batch column. fp16 state (64B/row,
// 3.2MB L2-resident). Software-pipelined unroll-8, fp32 accumulation.
// Epilogue: out = acc*outScale + bias[r]*biasScale (scaled-state scheme).
template <int WITH_BIAS>
__global__ __launch_bounds__(256) void spmm_kernel(
        const unsigned* __restrict__ kv, const int* __restrict__ row_start,
        const _Float16* __restrict__ in, _Float16* __restrict__ out,
        const float* __restrict__ bias, float outScale, float biasScale) {
    int t = blockIdx.x * 256 + threadIdx.x;
    int r = t >> 5;
    int b = t & 31;
    if (r >= NN) return;
    int s = clampi(row_start[r], NNZ_E);
    int e = clampi(row_start[r + 1], NNZ_E);
    if (e < s) e = s;
    float acc0 = 0.0f;
    float acc1 = 0.0f;
    int efull = s + ((e - s) & ~7);
    int i = s;
    unsigned k[8];
    if (i < efull) {
#pragma unroll
        for (int j = 0; j < 8; ++j) k[j] = kv[i + j];
    }
    while (i < efull) {
        float g[8];
#pragma unroll
        for (int j = 0; j < 8; ++j) g[j] = (float)in[((k[j] & 0xFFFFu) << 5) + b];
        i += 8;
        unsigned kn[8];
        if (i < efull) {
#pragma unroll
            for (int j = 0; j < 8; ++j) kn[j] = kv[i + j];
        }
#pragma unroll
        for (int j = 0; j < 8; ++j) {
            if (j & 1) acc1 += kv_val(k[j]) * g[j];
            else       acc0 += kv_val(k[j]) * g[j];
        }
#pragma unroll
        for (int j = 0; j < 8; ++j) k[j] = kn[j];
    }
    for (; i < e; ++i) {
        unsigned kk = kv[i];
        acc0 += kv_val(kk) * (float)in[((kk & 0xFFFFu) << 5) + b];
    }
    float res = (acc0 + acc1) * outScale;
    if (WITH_BIAS) res += bias[r] * biasScale;
    out[(r << 5) + b] = (_Float16)res;
}

// Final: out = state * 2^24 (undoes the cumulative 256^-3 state scaling).
__global__ void transpose_out_kernel(const _Float16* __restrict__ xt,
                                     float* __restrict__ out) {
    int i = blockIdx.x * blockDim.x + threadIdx.x;  // i = b*N + n (coalesced write)
    if (i < NB) {
        int b = i / NN;
        int n = i - b * NN;
        out[i] = (float)xt[(n << 5) + b] * 16777216.0f;
    }
}

extern "C" void kernel_launch(void* const* d_in, const int* in_sizes, int n_in,
                              void* d_out, int out_size, void* d_ws, size_t ws_size,
                              hipStream_t stream) {
    const float* x        = (const float*)d_in[0];
    const float* adj_vals = (const float*)d_in[1];
    const float* w_vals   = (const float*)d_in[2];
    const float* bias     = (const float*)d_in[3];
    const int*   row      = (const int*)d_in[4];
    const int*   col      = (const int*)d_in[5];
    float* out = (float*)d_out;

    // Workspace (~20 MB)
    unsigned*  k1        = (unsigned*)d_ws;          // NNZ_E -> becomes kvA
    unsigned*  aw1       = k1 + NNZ_E;               // NNZ_E -> becomes kvW
    _Float16*  xt16      = (_Float16*)(aw1 + NNZ_E); // NB fp16
    _Float16*  tmp16     = xt16 + NB;                // NB fp16
    int*   hist1         = (int*)(tmp16 + NB);       // NH (scanned in place)
    int*   bsumB         = hist1 + NH;               // 512
    int*   binstart      = bsumB + 512;              // NBIN+1 (+pad)
    int*   row_start     = binstart + NBIN + 8;      // NN+1

    const int BS = 256;
    const int grid_nb = (NB + BS - 1) / BS;          // 6250

    // ---- (chunk,bin) histogram matrix + bin-major scan ----
    hist_kernel<<<NBLK1, BS, 0, stream>>>(row, hist1);
    scan_local_kernel<<<SCAN_NBLK, BS, 0, stream>>>(hist1, NH, bsumB);
    scan_tops_kernel<<<1, 512, 0, stream>>>(bsumB, SCAN_NBLK);
    fin_add_kernel<<<SCAN_NBLK, BS, 0, stream>>>(hist1, NH, bsumB);
    binstart_kernel<<<(NBIN + 1 + BS - 1) / BS, BS, 0, stream>>>(hist1, binstart, row_start);

    // ---- two-pass sort: bin-group then row-sort + kv derive (in place) ----
    pass1_kernel<<<NBLK1, BS, 0, stream>>>(row, col, adj_vals, w_vals,
                                           hist1, k1, aw1);
    pass2_kernel<<<NBIN, BS, 0, stream>>>(k1, aw1, binstart, row_start);

    const unsigned* kvA = (const unsigned*)k1;
    const unsigned* kvW = (const unsigned*)aw1;

    // ---- dense passes (scaled fp16 state: state_l = xt_l * 256^-l) ----
    transpose_in_kernel<<<grid_nb, BS, 0, stream>>>(x, xt16);
    const float r256 = 1.0f / 256.0f;
    float biasScale = 1.0f;
    for (int layer = 0; layer < 3; ++layer) {
        biasScale *= r256;                   // 256^-(layer+1)
        spmm_kernel<0><<<grid_nb, BS, 0, stream>>>(kvW, row_start, xt16, tmp16,
                                                   nullptr, 1.0f, 0.0f);
        spmm_kernel<1><<<grid_nb, BS, 0, stream>>>(kvA, row_start, tmp16, xt16,
                                                   bias, r256, biasScale);
    }
    transpose_out_kernel<<<grid_nb, BS, 0, stream>>>(xt16, out);
}

// Round 14
// 285.378 us; speedup vs baseline: 1.3558x; 1.0353x over previous
//
#include <hip/hip_runtime.h>

// AdultConnectomeNetwork: 3 layers of xt = A_sp @ (W_sp @ xt) + bias.
// Round 14: row padding to multiple-of-8 + uint2 kv loads.
//  - Each row padded to a multiple of 8 edges with zero kv (col=0, val=0 —
//    exact no-op): spmm's scalar remainder tail (avg 3.5 serial edges/row,
//    ~comparable to the whole pipelined body) disappears; loop is a uniform
//    counted loop. row_desc[r] = start | (niters<<24): one load replaces
//    row_start[r] + row_start[r+1].
//  - Padded rows start 8-edge (32B) aligned -> kv loaded as uint2: 4
//    broadcast loads/iter instead of 8.
//  - Padded storage: fixed 6144-slot window per 128-row bin (mean 4092+448
//    pad, +28 sigma headroom), written by pass2.
//  - Scaled fp16 state from round 13 (state_l = xt_l*256^-l; exact pow2
//    rescale in epilogues; x2^24 at the end). Sort pipeline from round 13.
// Hardening: computed indices clamped (logic error -> absmax fail, not fault).

#define NN 50000
#define NNZ_E 1600000
#define NB (NN * 32)
#define CHUNK 6144
#define NBLK1 ((NNZ_E + CHUNK - 1) / CHUNK)      // 261
#define NBIN ((NN + 127) / 128)                  // 391 bins of 128 rows
#define NH (NBIN * NBLK1)                        // 102051
#define CAP2 5120                                // bin window cap (mean 4092, +16 sigma)
#define BCAP 6144                                // padded per-bin capacity
#define LENP (NBIN * BCAP)                       // 2402304 padded slots
#define LEN2 (LENP / 2)                          // uint2 count
#define SCAN_NBLK ((NH + 255) / 256)             // 399

__device__ __forceinline__ int clampi(int v, int hi) {  // [0, hi]
    v = v < 0 ? 0 : v;
    return v > hi ? hi : v;
}

__device__ __forceinline__ unsigned short f2h(float v) {
    union { _Float16 h; unsigned short u; } cv;
    cv.h = (_Float16)v;
    return cv.u;
}

__device__ __forceinline__ float kv_val(unsigned kv) {
    union { unsigned short u; _Float16 h; } cv;
    cv.u = (unsigned short)(kv >> 16);
    return (float)cv.h;
}

// Per-(chunk,bin) histogram matrix, bin-major. LDS only, no global atomics.
__global__ __launch_bounds__(256) void hist_kernel(const int* __restrict__ row,
                                                   int* __restrict__ hist1) {
    __shared__ int h[NBIN];
    int blk = blockIdx.x, tid = threadIdx.x;
    for (int j = tid; j < NBIN; j += 256) h[j] = 0;
    __syncthreads();
    int base = blk * CHUNK;
    int n = NNZ_E - base; if (n > CHUNK) n = CHUNK;
    for (int i = tid; i < n; i += 256)
        atomicAdd(&h[clampi(row[base + i], NN - 1) >> 7], 1);
    __syncthreads();
    for (int j = tid; j < NBIN; j += 256) hist1[j * NBLK1 + blk] = h[j];
}

// Exclusive scan within 256-blocks; bsum[blk] = block total.
__global__ void scan_local_kernel(int* __restrict__ data, int n, int* __restrict__ bsum) {
    __shared__ int s[256];
    int i = blockIdx.x * 256 + threadIdx.x;
    int v = (i < n) ? data[i] : 0;
    s[threadIdx.x] = v;
    __syncthreads();
    for (int off = 1; off < 256; off <<= 1) {
        int t = (threadIdx.x >= off) ? s[threadIdx.x - off] : 0;
        __syncthreads();
        s[threadIdx.x] += t;
        __syncthreads();
    }
    if (i < n) data[i] = s[threadIdx.x] - v;     // exclusive within block
    if (threadIdx.x == 255) bsum[blockIdx.x] = s[threadIdx.x];
}

// One block, 512 threads: exclusive scan of bsum[m], m <= 512 (m = 399).
__global__ void scan_tops_kernel(int* __restrict__ bsum, int m) {
    __shared__ int s[512];
    int t = threadIdx.x;
    int v = (t < m) ? bsum[t] : 0;
    s[t] = v;
    __syncthreads();
    for (int off = 1; off < 512; off <<= 1) {
        int u = (t >= off) ? s[t - off] : 0;
        __syncthreads();
        s[t] += u;
        __syncthreads();
    }
    if (t < m) bsum[t] = s[t] - v;               // exclusive
}

__global__ void fin_add_kernel(int* __restrict__ data, int n, const int* __restrict__ bsum) {
    int i = blockIdx.x * blockDim.x + threadIdx.x;
    if (i < n) data[i] += bsum[i >> 8];
}

// binstart[j] = scanned hist1[j*NBLK1].
__global__ void binstart_kernel(const int* __restrict__ hist1, int* __restrict__ binstart) {
    int j = blockIdx.x * blockDim.x + threadIdx.x;
    if (j < NBIN) binstart[j] = hist1[j * NBLK1];
    if (j == 0) binstart[NBIN] = NNZ_E;
}

// Pass 1: per-chunk in-LDS bin sort, payload staged as 8B/edge
// (key u32 + {fp16 a, fp16 w} u32); sequential reads, dense burst writes.
// key = (row<<16)|col (both < 2^16).
__global__ __launch_bounds__(256) void pass1_kernel(
        const int* __restrict__ row, const int* __restrict__ col,
        const float* __restrict__ a, const float* __restrict__ w,
        const int* __restrict__ hist1_off,
        unsigned* __restrict__ k1, unsigned* __restrict__ aw1) {
    __shared__ int h[NBIN];                  // counts -> placement cursors
    __shared__ int hscan[NBIN];              // block-local exclusive scan
    __shared__ int hoff[NBIN];               // global offsets for (bin, this blk)
    __shared__ int s256[256];
    __shared__ unsigned sKey[CHUNK];         // 24 KB
    __shared__ unsigned sAW[CHUNK];          // 24 KB
    int blk = blockIdx.x, tid = threadIdx.x;
    int base = blk * CHUNK;
    int n = NNZ_E - base; if (n > CHUNK) n = CHUNK;

    for (int j = tid; j < NBIN; j += 256) {
        h[j] = 0;
        hoff[j] = hist1_off[j * NBLK1 + blk];
    }
    __syncthreads();
    for (int i = tid; i < n; i += 256)
        atomicAdd(&h[clampi(row[base + i], NN - 1) >> 7], 1);
    __syncthreads();
    int j0 = tid * 2, j1 = tid * 2 + 1;
    int c0 = (j0 < NBIN) ? h[j0] : 0;
    int c1 = (j1 < NBIN) ? h[j1] : 0;
    int tsum = c0 + c1;
    s256[tid] = tsum;
    __syncthreads();
    for (int off = 1; off < 256; off <<= 1) {
        int t = (tid >= off) ? s256[tid - off] : 0;
        __syncthreads();
        s256[tid] += t;
        __syncthreads();
    }
    int ex = s256[tid] - tsum;
    __syncthreads();
    if (j0 < NBIN) { hscan[j0] = ex;      h[j0] = ex; }
    if (j1 < NBIN) { hscan[j1] = ex + c0; h[j1] = ex + c0; }
    __syncthreads();
    for (int i = tid; i < n; i += 256) {
        int r = clampi(row[base + i], NN - 1);
        int c = clampi(col[base + i], NN - 1);
        int bin = r >> 7;
        int p = atomicAdd(&h[bin], 1);       // LDS cursor, block-private
        p = clampi(p, n - 1);                // hardening
        sKey[p] = ((unsigned)r << 16) | (unsigned)c;
        sAW[p] = ((unsigned)f2h(a[base + i]) << 16) | (unsigned)f2h(w[base + i]);
    }
    __syncthreads();
    for (int p = tid; p < n; p += 256) {
        unsigned key = sKey[p];
        int bin = (int)(key >> 23);          // = row >> 7
        int d = clampi(hoff[bin] + (p - hscan[bin]), NNZ_E - 1);
        k1[d] = key;
        aw1[d] = sAW[p];
    }
}

// Pass 2: one block per 128-row bin. Row hist + padded-length scan in LDS,
// emits row_desc[r] = start | (niters<<24) and writes kvA2/kvW2 into the
// bin's fixed 6144-slot window with per-row multiple-of-8 padding (pad kv=0).
__global__ __launch_bounds__(256) void pass2_kernel(
        const unsigned* __restrict__ k1, const unsigned* __restrict__ aw1,
        const int* __restrict__ binstart,
        unsigned* __restrict__ kvA2, unsigned* __restrict__ kvW2,
        unsigned* __restrict__ row_desc) {
    __shared__ unsigned sKey[CAP2];          // 20 KB
    __shared__ unsigned sAW[CAP2];           // 20 KB
    __shared__ int rh[128];
    __shared__ int rs[128];
    __shared__ int cur[128];
    int bin = blockIdx.x, tid = threadIdx.x;
    int r0 = bin << 7;
    int rows = NN - r0; if (rows > 128) rows = 128;
    int base = clampi(binstart[bin], NNZ_E);
    int size = clampi(binstart[bin + 1], NNZ_E) - base;
    size = clampi(size, CAP2);               // hardening (always fits in practice)
    int pbase = bin * BCAP;

    if (tid < 128) rh[tid] = 0;
    __syncthreads();
    for (int i = tid; i < size; i += 256) {
        unsigned key = k1[base + i];
        atomicAdd(&rh[(key >> 16) & 127], 1);
        sKey[i] = key;
        sAW[i] = aw1[base + i];
    }
    __syncthreads();
    // padded lengths, exclusive scan over 128 rows
    int cnt  = (tid < 128) ? rh[tid] : 0;
    int plen = (cnt + 7) & ~7;
    if (tid < 128) rs[tid] = plen;
    __syncthreads();
    for (int off = 1; off < 128; off <<= 1) {
        int t = (tid >= off && tid < 128) ? rs[tid - off] : 0;
        __syncthreads();
        if (tid < 128) rs[tid] += t;
        __syncthreads();
    }
    int rofs = (tid < 128) ? clampi(rs[tid] - plen, BCAP - 8) : 0;
    if (tid < 128) cur[tid] = rofs;
    if (tid < rows)
        row_desc[r0 + tid] = (unsigned)(pbase + rofs) | ((unsigned)(plen >> 3) << 24);
    __syncthreads();
    // place edges (order within a row irrelevant)
    for (int i = tid; i < size; i += 256) {
        unsigned key = sKey[i];
        unsigned aw  = sAW[i];
        int rl = (key >> 16) & 127;
        int p = atomicAdd(&cur[rl], 1);
        p = clampi(p, BCAP - 1);             // hardening
        unsigned c = key & 0xFFFFu;
        kvA2[pbase + p] = (aw & 0xFFFF0000u) | c;
        kvW2[pbase + p] = (aw << 16) | c;
    }
    __syncthreads();
    // zero-fill pad slots (col=0, val=0 -> exact no-op in spmm)
    if (tid < rows) {
        int pl = (rh[tid] + 7) & ~7;
        for (int q = rh[tid]; q < pl; ++q) {
            int d = clampi(rofs + q, BCAP - 1);
            kvA2[pbase + d] = 0u;
            kvW2[pbase + d] = 0u;
        }
    }
}

__global__ void transpose_in_kernel(const float* __restrict__ x,
                                    _Float16* __restrict__ xt) {
    int i = blockIdx.x * blockDim.x + threadIdx.x;  // i = n*32 + b
    if (i < NB) {
        int n = i >> 5;
        int b = i & 31;
        xt[i] = (_Float16)x[b * NN + n];
    }
}

// One 32-lane half-wave per row. Uniform counted loop (rows padded to 8k
// edges), uint2 kv loads (4/iter), software-pipelined, fp32 accum.
// Epilogue: out = acc*outScale + bias[r]*biasScale (scaled-state scheme).
template <int WITH_BIAS>
__global__ __launch_bounds__(256) void spmm_kernel(
        const uint2* __restrict__ kv2, const unsigned* __restrict__ row_desc,
        const _Float16* __restrict__ in, _Float16* __restrict__ out,
        const float* __restrict__ bias, float outScale, float biasScale) {
    int t = blockIdx.x * 256 + threadIdx.x;
    int r = t >> 5;
    int b = t & 31;
    if (r >= NN) return;
    unsigned d = row_desc[r];
    int niter = (int)(d >> 24);                       // <= 255
    int base2 = clampi((int)(d & 0xFFFFFFu), LENP - 8) >> 1;  // 8-slot aligned
    float acc0 = 0.0f;
    float acc1 = 0.0f;
    uint2 k2[4];
    if (niter > 0) {
#pragma unroll
        for (int q = 0; q < 4; ++q) k2[q] = kv2[base2 + q];
    }
    for (int it = 0; it < niter; ++it) {
        unsigned k[8];
#pragma unroll
        for (int q = 0; q < 4; ++q) { k[2 * q] = k2[q].x; k[2 * q + 1] = k2[q].y; }
        float g[8];
#pragma unroll
        for (int j = 0; j < 8; ++j) g[j] = (float)in[((k[j] & 0xFFFFu) << 5) + b];
        if (it + 1 < niter) {
            int nb2 = base2 + (it + 1) * 4;
#pragma unroll
            for (int q = 0; q < 4; ++q) k2[q] = kv2[nb2 + q];
        }
#pragma unroll
        for (int j = 0; j < 8; ++j) {
            if (j & 1) acc1 += kv_val(k[j]) * g[j];
            else       acc0 += kv_val(k[j]) * g[j];
        }
    }
    float res = (acc0 + acc1) * outScale;
    if (WITH_BIAS) res += bias[r] * biasScale;
    out[(r << 5) + b] = (_Float16)res;
}

// Final: out = state * 2^24 (undoes the cumulative 256^-3 state scaling).
__global__ void transpose_out_kernel(const _Float16* __restrict__ xt,
                                     float* __restrict__ out) {
    int i = blockIdx.x * blockDim.x + threadIdx.x;  // i = b*N + n (coalesced write)
    if (i < NB) {
        int b = i / NN;
        int n = i - b * NN;
        out[i] = (float)xt[(n << 5) + b] * 16777216.0f;
    }
}

extern "C" void kernel_launch(void* const* d_in, const int* in_sizes, int n_in,
                              void* d_out, int out_size, void* d_ws, size_t ws_size,
                              hipStream_t stream) {
    const float* x        = (const float*)d_in[0];
    const float* adj_vals = (const float*)d_in[1];
    const float* w_vals   = (const float*)d_in[2];
    const float* bias     = (const float*)d_in[3];
    const int*   row      = (const int*)d_in[4];
    const int*   col      = (const int*)d_in[5];
    float* out = (float*)d_out;

    // Workspace (~40 MB of the 256 MiB ws)
    unsigned*  k1        = (unsigned*)d_ws;          // NNZ_E (sort keys)
    unsigned*  aw1       = k1 + NNZ_E;               // NNZ_E (packed fp16 a,w)
    unsigned*  kvA2      = aw1 + NNZ_E;              // LENP padded kv (A)
    unsigned*  kvW2      = kvA2 + LENP;              // LENP padded kv (W)
    _Float16*  xt16      = (_Float16*)(kvW2 + LENP); // NB fp16
    _Float16*  tmp16     = xt16 + NB;                // NB fp16
    int*   hist1         = (int*)(tmp16 + NB);       // NH (scanned in place)
    int*   bsumB         = hist1 + NH;               // 512
    int*   binstart      = bsumB + 512;              // NBIN+1 (+pad)
    unsigned* row_desc   = (unsigned*)(binstart + NBIN + 8);  // NN

    const int BS = 256;
    const int grid_nb = (NB + BS - 1) / BS;          // 6250

    // ---- (chunk,bin) histogram matrix + bin-major scan ----
    hist_kernel<<<NBLK1, BS, 0, stream>>>(row, hist1);
    scan_local_kernel<<<SCAN_NBLK, BS, 0, stream>>>(hist1, NH, bsumB);
    scan_tops_kernel<<<1, 512, 0, stream>>>(bsumB, SCAN_NBLK);
    fin_add_kernel<<<SCAN_NBLK, BS, 0, stream>>>(hist1, NH, bsumB);
    binstart_kernel<<<(NBIN + 1 + BS - 1) / BS, BS, 0, stream>>>(hist1, binstart);

    // ---- two-pass sort: bin-group then padded per-row placement ----
    pass1_kernel<<<NBLK1, BS, 0, stream>>>(row, col, adj_vals, w_vals,
                                           hist1, k1, aw1);
    pass2_kernel<<<NBIN, BS, 0, stream>>>(k1, aw1, binstart, kvA2, kvW2, row_desc);

    const uint2* kvA = (const uint2*)kvA2;
    const uint2* kvW = (const uint2*)kvW2;

    // ---- dense passes (scaled fp16 state: state_l = xt_l * 256^-l) ----
    transpose_in_kernel<<<grid_nb, BS, 0, stream>>>(x, xt16);
    const float r256 = 1.0f / 256.0f;
    float biasScale = 1.0f;
    for (int layer = 0; layer < 3; ++layer) {
        biasScale *= r256;                   // 256^-(layer+1)
        spmm_kernel<0><<<grid_nb, BS, 0, stream>>>(kvW, row_desc, xt16, tmp16,
                                                   nullptr, 1.0f, 0.0f);
        spmm_kernel<1><<<grid_nb, BS, 0, stream>>>(kvA, row_desc, tmp16, xt16,
                                                   bias, r256, biasScale);
    }
    transpose_out_kernel<<<grid_nb, BS, 0, stream>>>(xt16, out);
}

// Round 15
// 253.418 us; speedup vs baseline: 1.5268x; 1.1261x over previous
//
#include <hip/hip_runtime.h>

// AdultConnectomeNetwork: 3 layers of xt = A_sp @ (W_sp @ xt) + bias.
// Round 15: fp16x2 batch-pair lanes — 4 rows per wave64.
//  - SpMM: lane l in 0..15 owns batch columns (2l, 2l+1) as one fp16x2
//    dword. 16 lanes/row -> 4 rows/wave (was 2): per-row wave issue cost
//    ~halves (gathers 1 dword/lane, kv broadcasts serve 4 rows, packed
//    dword stores, NO cross-lane reduction). fp32 accumulation retained
//    via 2x v_cvt_f32_f16 unpack.
//  - Rows padded to multiple-of-8 edges (zero kv = exact no-op), uniform
//    counted loop, uint2 kv loads, software pipeline (round 14).
//  - Scaled fp16 state: state_l = xt_l*256^-l, exact pow2 rescale in
//    epilogues, x2^24 at the end (round 13; overflow-proof).
//  - Sort: two-pass LDS-staged counting sort (rounds 9-13).
// Hardening: computed indices clamped (logic error -> absmax fail, not fault).

#define NN 50000
#define NNZ_E 1600000
#define NB (NN * 32)
#define CHUNK 6144
#define NBLK1 ((NNZ_E + CHUNK - 1) / CHUNK)      // 261
#define NBIN ((NN + 127) / 128)                  // 391 bins of 128 rows
#define NH (NBIN * NBLK1)                        // 102051
#define CAP2 5120                                // bin window cap (mean 4092, +16 sigma)
#define BCAP 6144                                // padded per-bin capacity
#define LENP (NBIN * BCAP)                       // 2402304 padded slots
#define SCAN_NBLK ((NH + 255) / 256)             // 399

__device__ __forceinline__ int clampi(int v, int hi) {  // [0, hi]
    v = v < 0 ? 0 : v;
    return v > hi ? hi : v;
}

__device__ __forceinline__ unsigned short f2h(float v) {
    union { _Float16 h; unsigned short u; } cv;
    cv.h = (_Float16)v;
    return cv.u;
}

__device__ __forceinline__ float kv_val(unsigned kv) {
    union { unsigned short u; _Float16 h; } cv;
    cv.u = (unsigned short)(kv >> 16);
    return (float)cv.h;
}

// Per-(chunk,bin) histogram matrix, bin-major. LDS only, no global atomics.
__global__ __launch_bounds__(256) void hist_kernel(const int* __restrict__ row,
                                                   int* __restrict__ hist1) {
    __shared__ int h[NBIN];
    int blk = blockIdx.x, tid = threadIdx.x;
    for (int j = tid; j < NBIN; j += 256) h[j] = 0;
    __syncthreads();
    int base = blk * CHUNK;
    int n = NNZ_E - base; if (n > CHUNK) n = CHUNK;
    for (int i = tid; i < n; i += 256)
        atomicAdd(&h[clampi(row[base + i], NN - 1) >> 7], 1);
    __syncthreads();
    for (int j = tid; j < NBIN; j += 256) hist1[j * NBLK1 + blk] = h[j];
}

// Exclusive scan within 256-blocks; bsum[blk] = block total.
__global__ void scan_local_kernel(int* __restrict__ data, int n, int* __restrict__ bsum) {
    __shared__ int s[256];
    int i = blockIdx.x * 256 + threadIdx.x;
    int v = (i < n) ? data[i] : 0;
    s[threadIdx.x] = v;
    __syncthreads();
    for (int off = 1; off < 256; off <<= 1) {
        int t = (threadIdx.x >= off) ? s[threadIdx.x - off] : 0;
        __syncthreads();
        s[threadIdx.x] += t;
        __syncthreads();
    }
    if (i < n) data[i] = s[threadIdx.x] - v;     // exclusive within block
    if (threadIdx.x == 255) bsum[blockIdx.x] = s[threadIdx.x];
}

// One block, 512 threads: exclusive scan of bsum[m], m <= 512 (m = 399).
__global__ void scan_tops_kernel(int* __restrict__ bsum, int m) {
    __shared__ int s[512];
    int t = threadIdx.x;
    int v = (t < m) ? bsum[t] : 0;
    s[t] = v;
    __syncthreads();
    for (int off = 1; off < 512; off <<= 1) {
        int u = (t >= off) ? s[t - off] : 0;
        __syncthreads();
        s[t] += u;
        __syncthreads();
    }
    if (t < m) bsum[t] = s[t] - v;               // exclusive
}

__global__ void fin_add_kernel(int* __restrict__ data, int n, const int* __restrict__ bsum) {
    int i = blockIdx.x * blockDim.x + threadIdx.x;
    if (i < n) data[i] += bsum[i >> 8];
}

// binstart[j] = scanned hist1[j*NBLK1].
__global__ void binstart_kernel(const int* __restrict__ hist1, int* __restrict__ binstart) {
    int j = blockIdx.x * blockDim.x + threadIdx.x;
    if (j < NBIN) binstart[j] = hist1[j * NBLK1];
    if (j == 0) binstart[NBIN] = NNZ_E;
}

// Pass 1: per-chunk in-LDS bin sort, payload staged as 8B/edge
// (key u32 + {fp16 a, fp16 w} u32); sequential reads, dense burst writes.
// key = (row<<16)|col (both < 2^16).
__global__ __launch_bounds__(256) void pass1_kernel(
        const int* __restrict__ row, const int* __restrict__ col,
        const float* __restrict__ a, const float* __restrict__ w,
        const int* __restrict__ hist1_off,
        unsigned* __restrict__ k1, unsigned* __restrict__ aw1) {
    __shared__ int h[NBIN];                  // counts -> placement cursors
    __shared__ int hscan[NBIN];              // block-local exclusive scan
    __shared__ int hoff[NBIN];               // global offsets for (bin, this blk)
    __shared__ int s256[256];
    __shared__ unsigned sKey[CHUNK];         // 24 KB
    __shared__ unsigned sAW[CHUNK];          // 24 KB
    int blk = blockIdx.x, tid = threadIdx.x;
    int base = blk * CHUNK;
    int n = NNZ_E - base; if (n > CHUNK) n = CHUNK;

    for (int j = tid; j < NBIN; j += 256) {
        h[j] = 0;
        hoff[j] = hist1_off[j * NBLK1 + blk];
    }
    __syncthreads();
    for (int i = tid; i < n; i += 256)
        atomicAdd(&h[clampi(row[base + i], NN - 1) >> 7], 1);
    __syncthreads();
    int j0 = tid * 2, j1 = tid * 2 + 1;
    int c0 = (j0 < NBIN) ? h[j0] : 0;
    int c1 = (j1 < NBIN) ? h[j1] : 0;
    int tsum = c0 + c1;
    s256[tid] = tsum;
    __syncthreads();
    for (int off = 1; off < 256; off <<= 1) {
        int t = (tid >= off) ? s256[tid - off] : 0;
        __syncthreads();
        s256[tid] += t;
        __syncthreads();
    }
    int ex = s256[tid] - tsum;
    __syncthreads();
    if (j0 < NBIN) { hscan[j0] = ex;      h[j0] = ex; }
    if (j1 < NBIN) { hscan[j1] = ex + c0; h[j1] = ex + c0; }
    __syncthreads();
    for (int i = tid; i < n; i += 256) {
        int r = clampi(row[base + i], NN - 1);
        int c = clampi(col[base + i], NN - 1);
        int bin = r >> 7;
        int p = atomicAdd(&h[bin], 1);       // LDS cursor, block-private
        p = clampi(p, n - 1);                // hardening
        sKey[p] = ((unsigned)r << 16) | (unsigned)c;
        sAW[p] = ((unsigned)f2h(a[base + i]) << 16) | (unsigned)f2h(w[base + i]);
    }
    __syncthreads();
    for (int p = tid; p < n; p += 256) {
        unsigned key = sKey[p];
        int bin = (int)(key >> 23);          // = row >> 7
        int d = clampi(hoff[bin] + (p - hscan[bin]), NNZ_E - 1);
        k1[d] = key;
        aw1[d] = sAW[p];
    }
}

// Pass 2: one block per 128-row bin. Row hist + padded-length scan in LDS,
// emits row_desc[r] = start | (niters<<24) and writes kvA2/kvW2 into the
// bin's fixed 6144-slot window with per-row multiple-of-8 padding (pad kv=0).
__global__ __launch_bounds__(256) void pass2_kernel(
        const unsigned* __restrict__ k1, const unsigned* __restrict__ aw1,
        const int* __restrict__ binstart,
        unsigned* __restrict__ kvA2, unsigned* __restrict__ kvW2,
        unsigned* __restrict__ row_desc) {
    __shared__ unsigned sKey[CAP2];          // 20 KB
    __shared__ unsigned sAW[CAP2];           // 20 KB
    __shared__ int rh[128];
    __shared__ int rs[128];
    __shared__ int cur[128];
    int bin = blockIdx.x, tid = threadIdx.x;
    int r0 = bin << 7;
    int rows = NN - r0; if (rows > 128) rows = 128;
    int base = clampi(binstart[bin], NNZ_E);
    int size = clampi(binstart[bin + 1], NNZ_E) - base;
    size = clampi(size, CAP2);               // hardening (always fits in practice)
    int pbase = bin * BCAP;

    if (tid < 128) rh[tid] = 0;
    __syncthreads();
    for (int i = tid; i < size; i += 256) {
        unsigned key = k1[base + i];
        atomicAdd(&rh[(key >> 16) & 127], 1);
        sKey[i] = key;
        sAW[i] = aw1[base + i];
    }
    __syncthreads();
    int cnt  = (tid < 128) ? rh[tid] : 0;
    int plen = (cnt + 7) & ~7;
    if (tid < 128) rs[tid] = plen;
    __syncthreads();
    for (int off = 1; off < 128; off <<= 1) {
        int t = (tid >= off && tid < 128) ? rs[tid - off] : 0;
        __syncthreads();
        if (tid < 128) rs[tid] += t;
        __syncthreads();
    }
    int rofs = (tid < 128) ? clampi(rs[tid] - plen, BCAP - 8) : 0;
    if (tid < 128) cur[tid] = rofs;
    if (tid < rows)
        row_desc[r0 + tid] = (unsigned)(pbase + rofs) | ((unsigned)(plen >> 3) << 24);
    __syncthreads();
    for (int i = tid; i < size; i += 256) {
        unsigned key = sKey[i];
        unsigned aw  = sAW[i];
        int rl = (key >> 16) & 127;
        int p = atomicAdd(&cur[rl], 1);
        p = clampi(p, BCAP - 1);             // hardening
        unsigned c = key & 0xFFFFu;
        kvA2[pbase + p] = (aw & 0xFFFF0000u) | c;
        kvW2[pbase + p] = (aw << 16) | c;
    }
    __syncthreads();
    if (tid < rows) {
        int pl = (rh[tid] + 7) & ~7;
        for (int q = rh[tid]; q < pl; ++q) {
            int d = clampi(rofs + q, BCAP - 1);
            kvA2[pbase + d] = 0u;
            kvW2[pbase + d] = 0u;
        }
    }
}

__global__ void transpose_in_kernel(const float* __restrict__ x,
                                    _Float16* __restrict__ xt) {
    int i = blockIdx.x * blockDim.x + threadIdx.x;  // i = n*32 + b
    if (i < NB) {
        int n = i >> 5;
        int b = i & 31;
        xt[i] = (_Float16)x[b * NN + n];
    }
}

// 16 lanes per row; lane l owns batch pair (2l, 2l+1) as one fp16x2 dword.
// 4 rows per wave64. Uniform counted loop (rows padded to 8k edges), uint2
// kv loads, software-pipelined, fp32 accumulation, packed dword store.
// Epilogue: out = acc*outScale + bias[r]*biasScale (scaled-state scheme).
template <int WITH_BIAS>
__global__ __launch_bounds__(256) void spmm_kernel(
        const uint2* __restrict__ kv2, const unsigned* __restrict__ row_desc,
        const unsigned* __restrict__ in32, unsigned* __restrict__ out32,
        const float* __restrict__ bias, float outScale, float biasScale) {
    int t = blockIdx.x * 256 + threadIdx.x;
    int r = t >> 4;                          // one row per 16 lanes
    int l = t & 15;                          // batch-pair index
    if (r >= NN) return;
    unsigned d = row_desc[r];
    int niter = (int)(d >> 24);
    int base2 = clampi((int)(d & 0xFFFFFFu), LENP - 8) >> 1;  // 8-slot aligned
    float accL = 0.0f, accH = 0.0f;          // batch 2l, 2l+1
    uint2 k2[4];
    if (niter > 0) {
#pragma unroll
        for (int q = 0; q < 4; ++q) k2[q] = kv2[base2 + q];
    }
    for (int it = 0; it < niter; ++it) {
        unsigned k[8];
#pragma unroll
        for (int q = 0; q < 4; ++q) { k[2 * q] = k2[q].x; k[2 * q + 1] = k2[q].y; }
        unsigned gd[8];
#pragma unroll
        for (int j = 0; j < 8; ++j) gd[j] = in32[((k[j] & 0xFFFFu) << 4) + l];
        if (it + 1 < niter) {
            int nb2 = base2 + (it + 1) * 4;
#pragma unroll
            for (int q = 0; q < 4; ++q) k2[q] = kv2[nb2 + q];
        }
#pragma unroll
        for (int j = 0; j < 8; ++j) {
            float v = kv_val(k[j]);
            union { unsigned u; _Float16 h[2]; } cv;
            cv.u = gd[j];
            accL += v * (float)cv.h[0];
            accH += v * (float)cv.h[1];
        }
    }
    float rL = accL * outScale, rH = accH * outScale;
    if (WITH_BIAS) {
        float bb = bias[r] * biasScale;
        rL += bb; rH += bb;
    }
    union { unsigned u; _Float16 h[2]; } o;
    o.h[0] = (_Float16)rL;
    o.h[1] = (_Float16)rH;
    out32[(r << 4) + l] = o.u;
}

// Final: out = state * 2^24 (undoes the cumulative 256^-3 state scaling).
__global__ void transpose_out_kernel(const _Float16* __restrict__ xt,
                                     float* __restrict__ out) {
    int i = blockIdx.x * blockDim.x + threadIdx.x;  // i = b*N + n (coalesced write)
    if (i < NB) {
        int b = i / NN;
        int n = i - b * NN;
        out[i] = (float)xt[(n << 5) + b] * 16777216.0f;
    }
}

extern "C" void kernel_launch(void* const* d_in, const int* in_sizes, int n_in,
                              void* d_out, int out_size, void* d_ws, size_t ws_size,
                              hipStream_t stream) {
    const float* x        = (const float*)d_in[0];
    const float* adj_vals = (const float*)d_in[1];
    const float* w_vals   = (const float*)d_in[2];
    const float* bias     = (const float*)d_in[3];
    const int*   row      = (const int*)d_in[4];
    const int*   col      = (const int*)d_in[5];
    float* out = (float*)d_out;

    // Workspace (~40 MB of the 256 MiB ws)
    unsigned*  k1        = (unsigned*)d_ws;          // NNZ_E (sort keys)
    unsigned*  aw1       = k1 + NNZ_E;               // NNZ_E (packed fp16 a,w)
    unsigned*  kvA2      = aw1 + NNZ_E;              // LENP padded kv (A)
    unsigned*  kvW2      = kvA2 + LENP;              // LENP padded kv (W)
    _Float16*  xt16      = (_Float16*)(kvW2 + LENP); // NB fp16
    _Float16*  tmp16     = xt16 + NB;                // NB fp16
    int*   hist1         = (int*)(tmp16 + NB);       // NH (scanned in place)
    int*   bsumB         = hist1 + NH;               // 512
    int*   binstart      = bsumB + 512;              // NBIN+1 (+pad)
    unsigned* row_desc   = (unsigned*)(binstart + NBIN + 8);  // NN

    const int BS = 256;
    const int grid_nb   = (NB + BS - 1) / BS;        // 6250
    const int grid_spmm = (NN * 16 + BS - 1) / BS;   // 3125

    // ---- (chunk,bin) histogram matrix + bin-major scan ----
    hist_kernel<<<NBLK1, BS, 0, stream>>>(row, hist1);
    scan_local_kernel<<<SCAN_NBLK, BS, 0, stream>>>(hist1, NH, bsumB);
    scan_tops_kernel<<<1, 512, 0, stream>>>(bsumB, SCAN_NBLK);
    fin_add_kernel<<<SCAN_NBLK, BS, 0, stream>>>(hist1, NH, bsumB);
    binstart_kernel<<<(NBIN + 1 + BS - 1) / BS, BS, 0, stream>>>(hist1, binstart);

    // ---- two-pass sort: bin-group then padded per-row placement ----
    pass1_kernel<<<NBLK1, BS, 0, stream>>>(row, col, adj_vals, w_vals,
                                           hist1, k1, aw1);
    pass2_kernel<<<NBIN, BS, 0, stream>>>(k1, aw1, binstart, kvA2, kvW2, row_desc);

    const uint2* kvA = (const uint2*)kvA2;
    const uint2* kvW = (const uint2*)kvW2;
    const unsigned* xt32  = (const unsigned*)xt16;
    unsigned*       xt32w = (unsigned*)xt16;
    const unsigned* tm32  = (const unsigned*)tmp16;
    unsigned*       tm32w = (unsigned*)tmp16;

    // ---- dense passes (scaled fp16 state: state_l = xt_l * 256^-l) ----
    transpose_in_kernel<<<grid_nb, BS, 0, stream>>>(x, xt16);
    const float r256 = 1.0f / 256.0f;
    float biasScale = 1.0f;
    for (int layer = 0; layer < 3; ++layer) {
        biasScale *= r256;                   // 256^-(layer+1)
        spmm_kernel<0><<<grid_spmm, BS, 0, stream>>>(kvW, row_desc, xt32, tm32w,
                                                     nullptr, 1.0f, 0.0f);
        spmm_kernel<1><<<grid_spmm, BS, 0, stream>>>(kvA, row_desc, tm32, xt32w,
                                                     bias, r256, biasScale);
    }
    transpose_out_kernel<<<grid_nb, BS, 0, stream>>>(xt16, out);
}